// Round 10
// baseline (93.976 us; speedup 1.0000x reference)
//
#include <hip/hip_runtime.h>

#define B_   16
#define T_   2500
#define X_   512
#define XT   32
#define SEGS 4
#define SEGR 640
#define NSX  (X_ / XT)            // 16
#define NBLK (B_ * SEGS * NSX)    // 1024

typedef __attribute__((ext_vector_type(4))) float f32x4;

// lgkm-only barrier (verified r9): LDS producer->consumer visibility without
// draining vmcnt, so prefetched global loads stay in flight across it.
__device__ __forceinline__ void barrier_lgkm() {
    asm volatile("s_waitcnt lgkmcnt(0)\n\ts_barrier" ::: "memory");
}

// Round-10 = round-9 dataflow (fp8 ring, banded fp8 MFMA x/t-conv, DPP 4x4
// transpose ring writes, static producer/consumer pairs, 1-period prefetch,
// XCD swizzle, lgkm barriers) restructured into TWO phases per period to cut
// LDS 36.9 -> 25.6 KB -> 6 blocks/CU (was 4):
//   phase A: producers: products(p) -> PB (single buffer), issue loads(p+1)
//            consumers: tconv strip m=p-8 (reads all 16 ring slots; the slots
//            producers will overwrite are only touched in phase B)
//   [mid barrier]
//   phase B: producers: xconv(p) reads PB, writes ring slots gb, gb+1
//            consumers: pointwise coherence on acc (registers only)
//   [end barrier]
// Ring = 16 slots (mod-16 = AND); group 2m+4c+g -> slot (gb+4c+g)&15, and
// 4c+g enumerates 0..15 bijectively. Gaussian tables now live in registers
// (one-time expf loops; no LDS, no init barriers). Uniform fast/guarded
// branches for row bounds (only seg edges) and pointwise t<t_end (last strip
// of seg 3 only).
__global__ __launch_bounds__(256, 6) void coh10(const float* __restrict__ xg,
                                                const float* __restrict__ yg,
                                                float* __restrict__ partial)
{
    __shared__ unsigned long long XS[16][5][32];  // 20480 B fp8 ring: byte rs of [slot][f][col] = row-slot
    __shared__ unsigned long long PB[5][16][9];   //  5760 B fp8 products; byte j of row = staged col j
    __shared__ float wred[4];

    const int tid  = threadIdx.x;
    const int lane = tid & 63;
    const int w    = tid >> 6;
    const int g    = lane >> 4;
    const int ln16 = lane & 15;
    const int pair = w >> 1;
    const int p01  = w & 1;

    // ---- XCD-aware bijective block swizzle (1024 blocks, 8 XCDs) ----
    const int bid = blockIdx.x;
    const int wid = (bid & 7) * (NBLK / 8) + (bid >> 3);
    const int xt  = wid & 15;
    const int seg = (wid >> 4) & 3;
    const int b   = wid >> 6;

    const int x0    = xt * XT;
    const int t0    = seg * SEGR;
    const int t_end = min(t0 + SEGR, T_);
    const int nm    = (t_end - t0 + 15) >> 4;   // strips in this segment
    const int pmax  = nm + 7;

    const float* xb = xg + (size_t)b * T_ * X_;
    const float* yb = yg + (size_t)b * T_ * X_;

    float local = 0.f;

    if (pair == 0) {
        // ===================== producer =====================
        // kx normalization (registers, one-time)
        float ksum_x = 0.f;
#pragma unroll 1
        for (int i = 0; i < 11; ++i) { float d = (float)(i - 5); ksum_x += expf(-d * d * (1.0f / 242.0f)); }
        const float scx = 16.0f / ksum_x;
        // X-conv A fragment: A[m][k] = kx[k-m-3] * 16, fp8; k = 8g+sl, m = ln16
        long a_x;
        {
            float vv[8];
#pragma unroll
            for (int sl = 0; sl < 8; ++sl) {
                int idx = 8 * g + sl - ln16 - 3;
                float d = (float)(idx - 5);
                float v = expf(-d * d * (1.0f / 242.0f)) * scx;
                vv[sl] = (idx >= 0 && idx <= 10) ? v : 0.0f;
            }
            int lo = __builtin_amdgcn_cvt_pk_fp8_f32(vv[0], vv[1], 0, false);
            lo     = __builtin_amdgcn_cvt_pk_fp8_f32(vv[2], vv[3], lo, true);
            int hi = __builtin_amdgcn_cvt_pk_fp8_f32(vv[4], vv[5], 0, false);
            hi     = __builtin_amdgcn_cvt_pk_fp8_f32(vv[6], vv[7], hi, true);
            a_x = (long)(((unsigned long long)(unsigned)hi << 32) | (unsigned)lo);
        }
        // DPP 4x4 byte-transpose constants (verified r5-r9)
        const uint sel1  = (ln16 & 1) ? 0x07030602u : 0x01050004u;
        const uint sel2  = (ln16 & 2) ? 0x07060302u : 0x01000504u;
        const int  cidx  = ((ln16 & 1) << 1) | ((ln16 >> 1) & 1);
        const int  abyte = (ln16 & 4);
        const int  uhalf = (ln16 >> 3);

        const int  gcol  = x0 - 16 + 4 * ln16;
        const bool colOK = (gcol >= 0) && (gcol < X_);
        const float* xpl = xb + gcol;
        const float* ypl = yb + gcol;
        const float4 z4  = make_float4(0.f, 0.f, 0.f, 0.f);

        float4 xv[2], yv[2];
        auto issue_loads = [&](int c) {
            const int rowlo = t0 - 56 + 16 * c;
            if (rowlo >= 0 && rowlo + 15 < T_) {          // fast: rows all in-bounds
#pragma unroll
                for (int s = 0; s < 2; ++s) {
                    int grow = rowlo + 8 * p01 + 4 * s + g;
                    xv[s] = colOK ? *(const float4*)(xpl + (size_t)grow * X_) : z4;
                    yv[s] = colOK ? *(const float4*)(ypl + (size_t)grow * X_) : z4;
                }
            } else {                                       // guarded (seg edges only)
#pragma unroll
                for (int s = 0; s < 2; ++s) {
                    int grow = rowlo + 8 * p01 + 4 * s + g;
                    bool ok = colOK && (grow >= 0) && (grow < T_);
                    xv[s] = ok ? *(const float4*)(xpl + (size_t)grow * X_) : z4;
                    yv[s] = ok ? *(const float4*)(ypl + (size_t)grow * X_) : z4;
                }
            }
        };
        issue_loads(0);   // prologue

        int gb = 0;
        for (int p = 0; p <= pmax; ++p) {
            // ---- phase A: products(p) -> PB; issue loads(p+1) ----
            if (p <= nm + 6) {
#pragma unroll
                for (int s = 0; s < 2; ++s) {
                    int rrs = 8 * p01 + 4 * s + g;
                    float4 X = xv[s], Y = yv[s];
                    int q0 = __builtin_amdgcn_cvt_pk_fp8_f32(X.x, X.y, 0, false);
                    q0     = __builtin_amdgcn_cvt_pk_fp8_f32(X.z, X.w, q0, true);
                    int q1 = __builtin_amdgcn_cvt_pk_fp8_f32(Y.x, Y.y, 0, false);
                    q1     = __builtin_amdgcn_cvt_pk_fp8_f32(Y.z, Y.w, q1, true);
                    int q2 = __builtin_amdgcn_cvt_pk_fp8_f32(X.x * X.x, X.y * X.y, 0, false);
                    q2     = __builtin_amdgcn_cvt_pk_fp8_f32(X.z * X.z, X.w * X.w, q2, true);
                    int q3 = __builtin_amdgcn_cvt_pk_fp8_f32(Y.x * Y.x, Y.y * Y.y, 0, false);
                    q3     = __builtin_amdgcn_cvt_pk_fp8_f32(Y.z * Y.z, Y.w * Y.w, q3, true);
                    int q4 = __builtin_amdgcn_cvt_pk_fp8_f32(X.x * Y.x, X.y * Y.y, 0, false);
                    q4     = __builtin_amdgcn_cvt_pk_fp8_f32(X.z * Y.z, X.w * Y.w, q4, true);
                    *(uint*)((uchar*)&PB[0][rrs][0] + 4 * ln16) = (uint)q0;
                    *(uint*)((uchar*)&PB[1][rrs][0] + 4 * ln16) = (uint)q1;
                    *(uint*)((uchar*)&PB[2][rrs][0] + 4 * ln16) = (uint)q2;
                    *(uint*)((uchar*)&PB[3][rrs][0] + 4 * ln16) = (uint)q3;
                    *(uint*)((uchar*)&PB[4][rrs][0] + 4 * ln16) = (uint)q4;
                }
            }
            if (p + 1 <= nm + 6) issue_loads(p + 1);
            barrier_lgkm();
            // ---- phase B: xconv(p) -> ring slots gb (rows 0-7), gb+1 (rows 8-15) ----
            if (p <= nm + 6) {
                const int uu = (gb + uhalf) & 15;
#pragma unroll
                for (int f = 0; f < 5; ++f) {
                    long bfrag = (long)PB[f][ln16][1 + 2 * p01 + g];
                    f32x4 z; z[0] = 0.f; z[1] = 0.f; z[2] = 0.f; z[3] = 0.f;
                    f32x4 d = __builtin_amdgcn_mfma_f32_16x16x32_fp8_fp8(a_x, bfrag, z, 0, 0, 0);
                    int pk = __builtin_amdgcn_cvt_pk_fp8_f32(d[0], d[1], 0, false);
                    pk     = __builtin_amdgcn_cvt_pk_fp8_f32(d[2], d[3], pk, true);
                    uint pkc   = (uint)pk;
                    uint part1 = (uint)__builtin_amdgcn_update_dpp(0, (int)pkc, 177, 0xF, 0xF, true);
                    uint s1v   = __builtin_amdgcn_perm(pkc, part1, sel1);
                    uint part2 = (uint)__builtin_amdgcn_update_dpp(0, (int)s1v, 78, 0xF, 0xF, true);
                    uint Tt    = __builtin_amdgcn_perm(s1v, part2, sel2);
                    *(uint*)((uchar*)&XS[uu][f][16 * p01 + 4 * g + cidx] + abyte) = Tt;
                }
            }
            barrier_lgkm();
            gb = (gb + 2) & 15;
        }
    } else {
        // ===================== consumer =====================
        // kt normalization (registers, one-time)
        float ksum_t = 0.f;
#pragma unroll 1
        for (int i = 0; i < 101; ++i) { float d = (float)(i - 50); ksum_t += expf(-d * d * (1.0f / 882.0f)); }
        const float sct = 16.0f / ksum_t;
        // T-conv A fragments: A[m][k] = kt[k-m-6+...] band * 16, fp8 (r4 convention)
        long a_t[4];
#pragma unroll
        for (int c = 0; c < 4; ++c) {
            float vv[8];
#pragma unroll
            for (int sl = 0; sl < 8; ++sl) {
                int idx = 32 * c + 8 * g + sl - ln16 - 6;
                float d = (float)(idx - 50);
                float v = expf(-d * d * (1.0f / 882.0f)) * sct;
                vv[sl] = (idx >= 0 && idx <= 100) ? v : 0.0f;
            }
            int lo = __builtin_amdgcn_cvt_pk_fp8_f32(vv[0], vv[1], 0, false);
            lo     = __builtin_amdgcn_cvt_pk_fp8_f32(vv[2], vv[3], lo, true);
            int hi = __builtin_amdgcn_cvt_pk_fp8_f32(vv[4], vv[5], 0, false);
            hi     = __builtin_amdgcn_cvt_pk_fp8_f32(vv[6], vv[7], hi, true);
            a_t[c] = (long)(((unsigned long long)(unsigned)hi << 32) | (unsigned)lo);
        }

        int gb = 0;
        for (int p = 0; p <= pmax; ++p) {
            f32x4 acc[5];
            // ---- phase A: tconv strip m = p-8 (all 16 slots ready) ----
            if (p >= 8) {
#pragma unroll
                for (int f = 0; f < 5; ++f) { acc[f][0] = 0.f; acc[f][1] = 0.f; acc[f][2] = 0.f; acc[f][3] = 0.f; }
#pragma unroll
                for (int c = 0; c < 4; ++c) {
                    int u = (gb + 4 * c + g) & 15;   // slot of group 2m+4c+g
#pragma unroll
                    for (int f = 0; f < 5; ++f) {
                        long bfrag = (long)XS[u][f][16 * p01 + ln16];
                        acc[f] = __builtin_amdgcn_mfma_f32_16x16x32_fp8_fp8(a_t[c], bfrag, acc[f], 0, 0, 0);
                    }
                }
            }
            barrier_lgkm();
            // ---- phase B: pointwise (registers only) ----
            if (p >= 8) {
                const int m = p - 8;
                const float s_ = 1.0f / 256.0f;   // undo kt(16)*kx(16) scaling
                if (16 * m + 15 < t_end - t0) {   // fast: whole strip valid
#pragma unroll
                    for (int r = 0; r < 4; ++r) {
                        float a0 = acc[0][r], a1 = acc[1][r];
                        float sa0 = a0 * s_, sa1 = a1 * s_;
                        float cov = fmaf(-sa0, a1, acc[4][r]);
                        float vx  = fmaf(-sa0, a0, acc[2][r]);
                        float vy  = fmaf(-sa1, a1, acc[3][r]);
                        local += 1.0f - cov * rsqrtf(fmaf(vx, vy, 6.5536e-5f));
                    }
                } else {                           // guarded (last strip of seg 3)
#pragma unroll
                    for (int r = 0; r < 4; ++r) {
                        int t = t0 + 16 * m + 4 * g + r;
                        if (t < t_end) {
                            float a0 = acc[0][r], a1 = acc[1][r];
                            float sa0 = a0 * s_, sa1 = a1 * s_;
                            float cov = fmaf(-sa0, a1, acc[4][r]);
                            float vx  = fmaf(-sa0, a0, acc[2][r]);
                            float vy  = fmaf(-sa1, a1, acc[3][r]);
                            local += 1.0f - cov * rsqrtf(fmaf(vx, vy, 6.5536e-5f));
                        }
                    }
                }
            }
            barrier_lgkm();
            gb = (gb + 2) & 15;
        }
    }

    // ---- block reduction ----
#pragma unroll
    for (int off = 32; off >= 1; off >>= 1) local += __shfl_down(local, off);
    if ((tid & 63) == 0) wred[tid >> 6] = local;
    __syncthreads();
    if (tid == 0)
        partial[wid] = wred[0] + wred[1] + wred[2] + wred[3];
}

__global__ __launch_bounds__(256) void coh_reduce(const float* __restrict__ partial,
                                                  float* __restrict__ out) {
    __shared__ float wred[4];
    const int tid = threadIdx.x;
    float s = 0.0f;
    for (int i = tid; i < NBLK; i += 256) s += partial[i];
#pragma unroll
    for (int off = 32; off >= 1; off >>= 1) s += __shfl_down(s, off);
    if ((tid & 63) == 0) wred[tid >> 6] = s;
    __syncthreads();
    if (tid == 0)
        out[0] = (wred[0] + wred[1] + wred[2] + wred[3]) *
                 (1.0f / ((float)B_ * (float)T_ * (float)X_));
}

extern "C" void kernel_launch(void* const* d_in, const int* in_sizes, int n_in,
                              void* d_out, int out_size, void* d_ws, size_t ws_size,
                              hipStream_t stream) {
    const float* x = (const float*)d_in[0];
    const float* y = (const float*)d_in[1];
    float* out = (float*)d_out;
    float* partial = (float*)d_ws;   // NBLK floats = 4 KB

    coh10<<<dim3(NBLK), 256, 0, stream>>>(x, y, partial);
    coh_reduce<<<1, 256, 0, stream>>>(partial, out);
}

// Round 11
// 62.005 us; speedup vs baseline: 1.5156x; 1.5156x over previous
//
#include <hip/hip_runtime.h>

#define B_   16
#define T_   2500
#define X_   512
#define XT   32
#define SEGS 4
#define SEGR 640
#define NSX  (X_ / XT)            // 16
#define NBLK (B_ * SEGS * NSX)    // 1024
#define RING 20

typedef __attribute__((ext_vector_type(4))) float f32x4;

// lgkm-only barrier (verified r9): LDS producer->consumer visibility without
// draining vmcnt, so prefetched global loads stay in flight across it.
__device__ __forceinline__ void barrier_lgkm() {
    asm volatile("s_waitcnt lgkmcnt(0)\n\ts_barrier" ::: "memory");
}

// Round-11 = round-9 dataflow byte-for-byte (fp8 ring, banded fp8 MFMA x/t-conv,
// DPP 4x4 transpose ring writes, static producer/consumer roles, 1-period load
// prefetch, XCD swizzle, lgkm barriers) + three schedule levers:
//  - role mixing: pair = (w>>1) ^ (wid&1). Co-resident blocks (consecutive wid
//    on a CU) swap roles, so each SIMD hosts producer AND consumer waves ->
//    MFMA/VALU work spreads across all 4 pipes (was: segregated on half).
//  - lag-2 decoupling: RING=20 slots; consumer strip m = p-10 reads groups
//    2m..2m+15 (slots gb..gb+15), producer writes groups 2p-2,2p-1 (slots
//    gb+18,gb+19) -> consumers depend on data TWO periods old; producer
//    lateness no longer serializes into the same-period consumer.
//  - consumer fragment pre-gather: all 20 ds_read_b64 -> statically-indexed
//    regs, then 20 MFMAs back-to-back (one lgkm wait, not 20 stalls).
__global__ __launch_bounds__(256, 4) void coh11(const float* __restrict__ xg,
                                                const float* __restrict__ yg,
                                                float* __restrict__ partial)
{
    __shared__ float ktn[104];
    __shared__ float kxn[12];
    __shared__ float norm2[2];
    __shared__ unsigned long long XS[RING][5][34];  // fp8 ring: byte rs of [slot][f][col] = row-slot
    __shared__ unsigned long long PBq[2][5][16][9]; // fp8 products ping-pong; 72B rows
    __shared__ float wred[4];

    const int tid  = threadIdx.x;
    const int lane = tid & 63;
    const int w    = tid >> 6;
    const int g    = lane >> 4;
    const int ln16 = lane & 15;
    const int p01  = w & 1;

    // ---- XCD-aware bijective block swizzle (1024 blocks, 8 XCDs) ----
    const int bid = blockIdx.x;
    const int wid = (bid & 7) * (NBLK / 8) + (bid >> 3);
    const int xt  = wid & 15;
    const int seg = (wid >> 4) & 3;
    const int b   = wid >> 6;

    const int pair = ((w >> 1) ^ wid) & 1;          // role-mixed across co-resident blocks

    const int x0    = xt * XT;
    const int t0    = seg * SEGR;
    const int t_end = min(t0 + SEGR, T_);
    const int nm    = (t_end - t0 + 15) >> 4;
    const int pmax  = nm + 9;

    // ---- normalized Gaussian tables ----
    if (tid < 104) ktn[tid] = 0.0f;
    if (tid < 12)  kxn[tid] = 0.0f;
    __syncthreads();
    if (tid < 101) { float d = (float)(tid - 50); ktn[tid] = expf(-d * d / (2.0f * 21.0f * 21.0f)); }
    if (tid < 11)  { float d = (float)(tid - 5);  kxn[tid] = expf(-d * d / (2.0f * 11.0f * 11.0f)); }
    __syncthreads();
    if (tid == 0) {
        float s = 0.f; for (int i = 0; i < 101; ++i) s += ktn[i]; norm2[0] = 1.0f / s;
        s = 0.f;       for (int i = 0; i < 11;  ++i) s += kxn[i]; norm2[1] = 1.0f / s;
    }
    __syncthreads();
    if (tid < 101) ktn[tid] *= norm2[0];
    if (tid < 11)  kxn[tid] *= norm2[1];
    __syncthreads();

    const float* xb = xg + (size_t)b * T_ * X_;
    const float* yb = yg + (size_t)b * T_ * X_;

    float local = 0.f;

    if (pair == 0) {
        // ===================== producer loop =====================
        long a_x;
        {
            float vv[8];
#pragma unroll
            for (int sl = 0; sl < 8; ++sl) {
                int idx = 8 * g + sl - ln16 - 3;
                vv[sl] = (idx >= 0 && idx <= 10) ? kxn[idx] * 16.0f : 0.0f;
            }
            int lo = __builtin_amdgcn_cvt_pk_fp8_f32(vv[0], vv[1], 0, false);
            lo     = __builtin_amdgcn_cvt_pk_fp8_f32(vv[2], vv[3], lo, true);
            int hi = __builtin_amdgcn_cvt_pk_fp8_f32(vv[4], vv[5], 0, false);
            hi     = __builtin_amdgcn_cvt_pk_fp8_f32(vv[6], vv[7], hi, true);
            a_x = (long)(((unsigned long long)(unsigned)hi << 32) | (unsigned)lo);
        }
        // DPP 4x4 byte-transpose constants (verified r5-r9)
        const uint sel1  = (ln16 & 1) ? 0x07030602u : 0x01050004u;
        const uint sel2  = (ln16 & 2) ? 0x07060302u : 0x01000504u;
        const int  cidx  = ((ln16 & 1) << 1) | ((ln16 >> 1) & 1);
        const int  abyte = (ln16 & 4);
        const int  uhalf = (ln16 >> 3);

        const int  gcol  = x0 - 16 + 4 * ln16;
        const bool colOK = (gcol >= 0) && (gcol < X_);

        float4 xv[2], yv[2];
        // prologue: issue loads for chunk 0
#pragma unroll
        for (int s = 0; s < 2; ++s) {
            int grow = t0 - 56 + 8 * p01 + 4 * s + g;
            bool ok = colOK && (grow >= 0) && (grow < T_);
            xv[s] = ok ? *(const float4*)(xb + (size_t)grow * X_ + gcol) : make_float4(0.f, 0.f, 0.f, 0.f);
            yv[s] = ok ? *(const float4*)(yb + (size_t)grow * X_ + gcol) : make_float4(0.f, 0.f, 0.f, 0.f);
        }

        int gb = 0;   // 2p mod RING
        for (int it = 0; it <= pmax; ++it) {
            // ---- xconv-MFMA of chunk it-1 -> ring slots gb+18, gb+19 (mod 20) ----
            if (it >= 1 && it <= nm + 7) {
                int u0 = gb + 18; if (u0 >= RING) u0 -= RING;   // even, <= 18
                const int uu = u0 + uhalf;                       // <= 19, no wrap
                const int sb = (it - 1) & 1;
#pragma unroll
                for (int f = 0; f < 5; ++f) {
                    long bfrag = (long)PBq[sb][f][ln16][1 + 2 * p01 + g];
                    f32x4 z; z[0] = 0.f; z[1] = 0.f; z[2] = 0.f; z[3] = 0.f;
                    f32x4 d = __builtin_amdgcn_mfma_f32_16x16x32_fp8_fp8(a_x, bfrag, z, 0, 0, 0);
                    int pk = __builtin_amdgcn_cvt_pk_fp8_f32(d[0], d[1], 0, false);
                    pk     = __builtin_amdgcn_cvt_pk_fp8_f32(d[2], d[3], pk, true);
                    uint pkc   = (uint)pk;
                    uint part1 = (uint)__builtin_amdgcn_update_dpp(0, (int)pkc, 177, 0xF, 0xF, true);
                    uint s1v   = __builtin_amdgcn_perm(pkc, part1, sel1);
                    uint part2 = (uint)__builtin_amdgcn_update_dpp(0, (int)s1v, 78, 0xF, 0xF, true);
                    uint Tt    = __builtin_amdgcn_perm(s1v, part2, sel2);
                    *(uint*)((uchar*)&XS[uu][f][16 * p01 + 4 * g + cidx] + abyte) = Tt;
                }
            }
            // ---- products of chunk it (consume loads issued one period ago) ----
            if (it <= nm + 6) {
                const int db = it & 1;
#pragma unroll
                for (int s = 0; s < 2; ++s) {
                    int rrs = 8 * p01 + 4 * s + g;
                    float4 X = xv[s], Y = yv[s];
                    int q0 = __builtin_amdgcn_cvt_pk_fp8_f32(X.x, X.y, 0, false);
                    q0     = __builtin_amdgcn_cvt_pk_fp8_f32(X.z, X.w, q0, true);
                    int q1 = __builtin_amdgcn_cvt_pk_fp8_f32(Y.x, Y.y, 0, false);
                    q1     = __builtin_amdgcn_cvt_pk_fp8_f32(Y.z, Y.w, q1, true);
                    int q2 = __builtin_amdgcn_cvt_pk_fp8_f32(X.x * X.x, X.y * X.y, 0, false);
                    q2     = __builtin_amdgcn_cvt_pk_fp8_f32(X.z * X.z, X.w * X.w, q2, true);
                    int q3 = __builtin_amdgcn_cvt_pk_fp8_f32(Y.x * Y.x, Y.y * Y.y, 0, false);
                    q3     = __builtin_amdgcn_cvt_pk_fp8_f32(Y.z * Y.z, Y.w * Y.w, q3, true);
                    int q4 = __builtin_amdgcn_cvt_pk_fp8_f32(X.x * Y.x, X.y * Y.y, 0, false);
                    q4     = __builtin_amdgcn_cvt_pk_fp8_f32(X.z * Y.z, X.w * Y.w, q4, true);
                    *(uint*)((uchar*)&PBq[db][0][rrs][0] + 4 * ln16) = (uint)q0;
                    *(uint*)((uchar*)&PBq[db][1][rrs][0] + 4 * ln16) = (uint)q1;
                    *(uint*)((uchar*)&PBq[db][2][rrs][0] + 4 * ln16) = (uint)q2;
                    *(uint*)((uchar*)&PBq[db][3][rrs][0] + 4 * ln16) = (uint)q3;
                    *(uint*)((uchar*)&PBq[db][4][rrs][0] + 4 * ln16) = (uint)q4;
                }
            }
            // ---- issue loads for chunk it+1 (stay in flight across the raw barrier) ----
            if (it + 1 <= nm + 6) {
#pragma unroll
                for (int s = 0; s < 2; ++s) {
                    int grow = t0 - 56 + 16 * (it + 1) + 8 * p01 + 4 * s + g;
                    bool ok = colOK && (grow >= 0) && (grow < T_);
                    xv[s] = ok ? *(const float4*)(xb + (size_t)grow * X_ + gcol) : make_float4(0.f, 0.f, 0.f, 0.f);
                    yv[s] = ok ? *(const float4*)(yb + (size_t)grow * X_ + gcol) : make_float4(0.f, 0.f, 0.f, 0.f);
                }
            }
            barrier_lgkm();
            gb += 2; if (gb >= RING) gb -= RING;
        }
    } else {
        // ===================== consumer loop =====================
        long a_t[4];
#pragma unroll
        for (int c = 0; c < 4; ++c) {
            float vv[8];
#pragma unroll
            for (int sl = 0; sl < 8; ++sl) {
                int idx = 32 * c + 8 * g + sl - ln16 - 6;
                vv[sl] = (idx >= 0 && idx <= 100) ? ktn[idx] * 16.0f : 0.0f;
            }
            int lo = __builtin_amdgcn_cvt_pk_fp8_f32(vv[0], vv[1], 0, false);
            lo     = __builtin_amdgcn_cvt_pk_fp8_f32(vv[2], vv[3], lo, true);
            int hi = __builtin_amdgcn_cvt_pk_fp8_f32(vv[4], vv[5], 0, false);
            hi     = __builtin_amdgcn_cvt_pk_fp8_f32(vv[6], vv[7], hi, true);
            a_t[c] = (long)(((unsigned long long)(unsigned)hi << 32) | (unsigned)lo);
        }

        int gb = 0;   // 2p mod RING; consumer strip m = p-10 starts at slot gb
        for (int it = 0; it <= pmax; ++it) {
            if (it >= 10) {
                const int m = it - 10;
                // pre-gather all 20 fragments (static indices), one lgkm wait
                long bf0[5], bf1[5], bf2[5], bf3[5];
                {
                    int u0 = gb + g;      if (u0 >= RING) u0 -= RING;
                    int u1 = gb + 4 + g;  if (u1 >= RING) u1 -= RING;
                    int u2 = gb + 8 + g;  if (u2 >= RING) u2 -= RING;
                    int u3 = gb + 12 + g; if (u3 >= RING) u3 -= RING;
                    const int nn = 16 * p01 + ln16;
#pragma unroll
                    for (int f = 0; f < 5; ++f) bf0[f] = (long)XS[u0][f][nn];
#pragma unroll
                    for (int f = 0; f < 5; ++f) bf1[f] = (long)XS[u1][f][nn];
#pragma unroll
                    for (int f = 0; f < 5; ++f) bf2[f] = (long)XS[u2][f][nn];
#pragma unroll
                    for (int f = 0; f < 5; ++f) bf3[f] = (long)XS[u3][f][nn];
                }
                f32x4 acc[5];
#pragma unroll
                for (int f = 0; f < 5; ++f) { acc[f][0] = 0.f; acc[f][1] = 0.f; acc[f][2] = 0.f; acc[f][3] = 0.f; }
#pragma unroll
                for (int f = 0; f < 5; ++f) acc[f] = __builtin_amdgcn_mfma_f32_16x16x32_fp8_fp8(a_t[0], bf0[f], acc[f], 0, 0, 0);
#pragma unroll
                for (int f = 0; f < 5; ++f) acc[f] = __builtin_amdgcn_mfma_f32_16x16x32_fp8_fp8(a_t[1], bf1[f], acc[f], 0, 0, 0);
#pragma unroll
                for (int f = 0; f < 5; ++f) acc[f] = __builtin_amdgcn_mfma_f32_16x16x32_fp8_fp8(a_t[2], bf2[f], acc[f], 0, 0, 0);
#pragma unroll
                for (int f = 0; f < 5; ++f) acc[f] = __builtin_amdgcn_mfma_f32_16x16x32_fp8_fp8(a_t[3], bf3[f], acc[f], 0, 0, 0);

                const float s_ = 1.0f / 256.0f;   // undo kt(16)*kx(16) scaling
#pragma unroll
                for (int r = 0; r < 4; ++r) {
                    int t = t0 + 16 * m + 4 * g + r;
                    if (t < t_end) {
                        float a0 = acc[0][r], a1 = acc[1][r];
                        float sa0 = a0 * s_, sa1 = a1 * s_;
                        float cov = fmaf(-sa0, a1, acc[4][r]);
                        float vx  = fmaf(-sa0, a0, acc[2][r]);
                        float vy  = fmaf(-sa1, a1, acc[3][r]);
                        local += 1.0f - cov * rsqrtf(fmaf(vx, vy, 6.5536e-5f));
                    }
                }
            }
            barrier_lgkm();
            gb += 2; if (gb >= RING) gb -= RING;
        }
    }

    // ---- block reduction ----
#pragma unroll
    for (int off = 32; off >= 1; off >>= 1) local += __shfl_down(local, off);
    if ((tid & 63) == 0) wred[tid >> 6] = local;
    __syncthreads();
    if (tid == 0)
        partial[wid] = wred[0] + wred[1] + wred[2] + wred[3];
}

__global__ __launch_bounds__(256) void coh_reduce(const float* __restrict__ partial,
                                                  float* __restrict__ out) {
    __shared__ float wred[4];
    const int tid = threadIdx.x;
    float s = 0.0f;
    for (int i = tid; i < NBLK; i += 256) s += partial[i];
#pragma unroll
    for (int off = 32; off >= 1; off >>= 1) s += __shfl_down(s, off);
    if ((tid & 63) == 0) wred[tid >> 6] = s;
    __syncthreads();
    if (tid == 0)
        out[0] = (wred[0] + wred[1] + wred[2] + wred[3]) *
                 (1.0f / ((float)B_ * (float)T_ * (float)X_));
}

extern "C" void kernel_launch(void* const* d_in, const int* in_sizes, int n_in,
                              void* d_out, int out_size, void* d_ws, size_t ws_size,
                              hipStream_t stream) {
    const float* x = (const float*)d_in[0];
    const float* y = (const float*)d_in[1];
    float* out = (float*)d_out;
    float* partial = (float*)d_ws;   // NBLK floats = 4 KB

    coh11<<<dim3(NBLK), 256, 0, stream>>>(x, y, partial);
    coh_reduce<<<1, 256, 0, stream>>>(partial, out);
}